// Round 8
// baseline (92.350 us; speedup 1.0000x reference)
//
#include <hip/hip_runtime.h>
#include <math.h>

#define BB 2
#define SS 512
#define HH 256
#define AA 128
#define CH 4                  // chunk rows (== output row-block, always aligned)
#define NCH (SS / CH)         // 128 chunks per batch
#define SENT 0x5E17CAFE       // != 0xAAAAAAAA harness poison -> no init needed

// ---------------------------------------------------------------------------
// One kernel, 256 blocks x 256 threads. Block (b,c):
//  Phase 1 (R5 k1 body): t/E/W for rows j0..j0+3, chunk partial C[c][h];
//    publish Ews chunk + Cws row, then release-store flags[b][c]=SENT.
//  Spin: thread tid<c polls flags[b][tid] (relaxed, agent scope) until SENT;
//    __syncthreads + one __threadfence gives acquire visibility (XCD-safe).
//  Phase 3 (R5 k2 body): P_i reduction, d rows (float4 stores), a rows via
//    8-way-ILP sum of C chunks < c + 4 incremental x rows.
// Deadlock-free: grid (256 blocks, ~12 KB LDS, moderate VGPR) is fully
// resident on 256 CUs regardless of dispatch order; every block publishes
// before it ever spins.
// ---------------------------------------------------------------------------
__global__ __launch_bounds__(256)
void k_fused(const float* __restrict__ x,
             const int* __restrict__ am,
             const float* __restrict__ w_a,
             const float* __restrict__ query,
             float* __restrict__ Ews,     // B*S
             float* __restrict__ Cws,     // B*NCH*H
             int*   __restrict__ flags,   // B*NCH
             float* __restrict__ dout,
             float* __restrict__ aout)
{
    const int blk  = blockIdx.x;           // 0..255
    const int b    = blk >> 7;
    const int c    = blk & 127;
    const int j0   = c * CH;               // == i0 for phase 3
    const int tid  = threadIdx.x;          // 0..255
    const int lane = tid & 63;
    const int wvi  = tid >> 6;

    __shared__ __align__(16) float xs[CH][HH];        // 4 KB
    __shared__ __align__(16) float sred[CH][2][AA];   // 4 KB
    __shared__ float Wl[CH];
    __shared__ float Es[SS];                          // 2 KB
    __shared__ __align__(16) float Ws[SS];            // 2 KB
    __shared__ float red[4];
    __shared__ float Pinv[4];

    // ================= Phase 1 (R5 k1 body, measured-best) =================
    {
        const int a    = tid & 127;
        const int half = tid >> 7;

        // stage 4 x-rows (contiguous 4 KB) as float4, coalesced
        const float4* xr4 = (const float4*)(x + (size_t)(b * SS + j0) * HH);
        ((float4*)&xs[0][0])[tid] = xr4[tid];
        __syncthreads();

        float acc0 = 0.f, acc1 = 0.f, acc2 = 0.f, acc3 = 0.f;
        const int hbase = half * 128;
        for (int hh = 0; hh < 128; hh += 4) {
            const int h = hbase + hh;
            const float w0 = w_a[(h + 0) * AA + a];   // coalesced, L2-hot
            const float w1 = w_a[(h + 1) * AA + a];
            const float w2 = w_a[(h + 2) * AA + a];
            const float w3 = w_a[(h + 3) * AA + a];
            const float4 x0 = *(const float4*)&xs[0][h];   // LDS broadcast
            const float4 x1 = *(const float4*)&xs[1][h];
            const float4 x2 = *(const float4*)&xs[2][h];
            const float4 x3 = *(const float4*)&xs[3][h];
            acc0 = fmaf(x0.x, w0, fmaf(x0.y, w1, fmaf(x0.z, w2, fmaf(x0.w, w3, acc0))));
            acc1 = fmaf(x1.x, w0, fmaf(x1.y, w1, fmaf(x1.z, w2, fmaf(x1.w, w3, acc1))));
            acc2 = fmaf(x2.x, w0, fmaf(x2.y, w1, fmaf(x2.z, w2, fmaf(x2.w, w3, acc2))));
            acc3 = fmaf(x3.x, w0, fmaf(x3.y, w1, fmaf(x3.z, w2, fmaf(x3.w, w3, acc3))));
        }
        sred[0][half][a] = acc0;
        sred[1][half][a] = acc1;
        sred[2][half][a] = acc2;
        sred[3][half][a] = acc3;
        __syncthreads();

        // wave wvi reduces row r=wvi; lane covers a in {lane, lane+64}
        {
            const int r = wvi;
            const float f0 = sred[r][0][lane]      + sred[r][1][lane];
            const float f1 = sred[r][0][lane + 64] + sred[r][1][lane + 64];
            float v = tanhf(f0) * query[lane] + tanhf(f1) * query[lane + 64];
            for (int off = 32; off > 0; off >>= 1)
                v += __shfl_down(v, off, 64);
            if (lane == 0) {
                const float e = expf(v);     // unshifted: |t| << 88 here
                Wl[r] = am[b * SS + j0 + r] ? e : 0.f;
                Ews[b * SS + j0 + r] = e;
            }
        }
        __syncthreads();

        // chunk partial C[h] = sum_r W[r]*x[r][h]; thread tid = h
        const float cacc = fmaf(Wl[0], xs[0][tid],
                           fmaf(Wl[1], xs[1][tid],
                           fmaf(Wl[2], xs[2][tid],
                                Wl[3] * xs[3][tid])));
        Cws[(size_t)(b * NCH + c) * HH + tid] = cacc;
    }

    // publish: barrier drains all the block's global stores (vmcnt(0) before
    // s_barrier), then one release-store makes them visible device-wide.
    __syncthreads();
    if (tid == 0)
        __hip_atomic_store(&flags[blk], SENT,
                           __ATOMIC_RELEASE, __HIP_MEMORY_SCOPE_AGENT);

    // ================= Spin on predecessor chunks =================
    if (tid < c) {
        const int* f = flags + (b << 7);
        while (__hip_atomic_load(&f[tid], __ATOMIC_RELAXED,
                                 __HIP_MEMORY_SCOPE_AGENT) != SENT)
            __builtin_amdgcn_s_sleep(1);
    }
    __syncthreads();
    __threadfence();   // acquire side: invalidate stale lines before reads

    // ================= Phase 3 (R5 k2 body, i0 = j0) =================
    {
        const int i0 = j0;

        const float e0 = Ews[b * SS + tid];          // unpublished entries are
        const float e1 = Ews[b * SS + tid + 256];    // ternary-masked below
        const int  am0 = am[b * SS + tid];
        const int  am1 = am[b * SS + tid + 256];
        Es[tid] = e0;             Es[tid + 256] = e1;
        Ws[tid] = am0 ? e0 : 0.f; Ws[tid + 256] = am1 ? e1 : 0.f;

        // P_base = sum_{j<=i0} E[j]   (only published chunks contribute)
        float p = ((tid <= i0) ? e0 : 0.f) + ((tid + 256 <= i0) ? e1 : 0.f);
        for (int off = 32; off > 0; off >>= 1)
            p += __shfl_down(p, off, 64);
        if (lane == 0) red[wvi] = p;
        __syncthreads();
        if (tid == 0) {
            const float P0 = red[0] + red[1] + red[2] + red[3];
            const float P1 = P0 + Es[i0 + 1];
            const float P2 = P1 + Es[i0 + 2];
            const float P3 = P2 + Es[i0 + 3];
            Pinv[0] = 1.f / P0; Pinv[1] = 1.f / P1;
            Pinv[2] = 1.f / P2; Pinv[3] = 1.f / P3;
        }
        __syncthreads();

        const int* amg = am + b * SS;
        int ami[4];
#pragma unroll
        for (int r = 0; r < 4; ++r) ami[r] = amg[i0 + r];

        // ---- d rows: float4 stores; thread -> (row-half, col4)
        const size_t drow = (size_t)(b * SS + i0) * SS;
        const int c4 = tid & 127;
        const int jc = c4 << 2;
        const float4 wv4 = *(const float4*)&Ws[jc];
#pragma unroll
        for (int pp = 0; pp < 2; ++pp) {
            const int   r  = (tid >> 7) + 2 * pp;
            const int   i  = i0 + r;
            const float pv = Pinv[r];
            const bool  on = ami[r] != 0;
            float4 o;
            o.x = (on && jc + 0 <= i) ? wv4.x * pv : 0.f;
            o.y = (on && jc + 1 <= i) ? wv4.y * pv : 0.f;
            o.z = (on && jc + 2 <= i) ? wv4.z * pv : 0.f;
            o.w = (on && jc + 3 <= i) ? wv4.w * pv : 0.f;
            *(float4*)&dout[drow + (size_t)r * SS + jc] = o;
        }

        // ---- a rows: 8-way-ILP sum of C chunks < c, then 4 raw x rows
        const int nfull = c;
        const float* xb = x + (size_t)b * SS * HH + tid;
        const float* Cb = Cws + (size_t)b * NCH * HH + tid;

        float s0 = 0.f, s1 = 0.f, s2 = 0.f, s3 = 0.f;
        float s4 = 0.f, s5 = 0.f, s6 = 0.f, s7 = 0.f;
        int cc = 0;
        for (; cc + 8 <= nfull; cc += 8) {
            s0 += Cb[(size_t)(cc + 0) * HH];
            s1 += Cb[(size_t)(cc + 1) * HH];
            s2 += Cb[(size_t)(cc + 2) * HH];
            s3 += Cb[(size_t)(cc + 3) * HH];
            s4 += Cb[(size_t)(cc + 4) * HH];
            s5 += Cb[(size_t)(cc + 5) * HH];
            s6 += Cb[(size_t)(cc + 6) * HH];
            s7 += Cb[(size_t)(cc + 7) * HH];
        }
        for (; cc < nfull; ++cc)
            s0 += Cb[(size_t)cc * HH];
        const float base = ((s0 + s1) + (s2 + s3)) + ((s4 + s5) + (s6 + s7));

        const float a0v = fmaf(Ws[i0],     xb[(size_t)(i0)     * HH], base);
        const float a1v = fmaf(Ws[i0 + 1], xb[(size_t)(i0 + 1) * HH], a0v);
        const float a2v = fmaf(Ws[i0 + 2], xb[(size_t)(i0 + 2) * HH], a1v);
        const float a3v = fmaf(Ws[i0 + 3], xb[(size_t)(i0 + 3) * HH], a2v);

        const size_t arow = (size_t)(b * SS + i0) * HH + tid;
        const float av[4] = {a0v, a1v, a2v, a3v};
#pragma unroll
        for (int r = 0; r < 4; ++r)
            aout[arow + (size_t)r * HH] = ami[r] ? av[r] * Pinv[r] : 0.f;
    }
}

// ---------------------------------------------------------------------------
extern "C" void kernel_launch(void* const* d_in, const int* in_sizes, int n_in,
                              void* d_out, int out_size, void* d_ws, size_t ws_size,
                              hipStream_t stream) {
    const float* x     = (const float*)d_in[0];
    const int*   am    = (const int*)d_in[1];
    const float* w_a   = (const float*)d_in[2];
    const float* query = (const float*)d_in[3];

    float* a_out  = (float*)d_out;                   // B*S*H
    float* d_outp = a_out + (size_t)BB * SS * HH;    // B*S*S

    float* Ews   = (float*)d_ws;                     // B*S floats
    float* Cws   = Ews + BB * SS;                    // B*NCH*H floats (256 KB)
    int*   flags = (int*)(Cws + (size_t)BB * NCH * HH);  // B*NCH ints

    k_fused<<<BB * NCH, 256, 0, stream>>>(x, am, w_a, query,
                                          Ews, Cws, flags, d_outp, a_out);
}

// Round 9
// 75.105 us; speedup vs baseline: 1.2296x; 1.2296x over previous
//
#include <hip/hip_runtime.h>
#include <math.h>

#define BB 2
#define SS 512
#define HH 256
#define AA 128
#define CH 4                  // chunk rows (== k2 row-block -> always aligned)
#define NCH (SS / CH)         // 128 chunks per batch

// ---------------------------------------------------------------------------
// Kernel 1: per 4-row chunk (256 blocks x 256 thr, full chip):
//   t[r]  = sum_a q[a] * tanh( sum_h x[j0+r,h] * w_a[h,a] )
//   E[r]  = exp(t[r])            (unshifted: |t| << 88 for this problem)
//   W[r]  = E[r] * am[j0+r]
//   C[h]  = sum_r W[r] * x[j0+r,h]
// [R5 measured-best body — R6/R7/R8 variants (scalar-path x loads, fusion,
//  spin-flags) all regressed; do not deviate.]
// ---------------------------------------------------------------------------
__global__ void k_tc(const float* __restrict__ x,
                     const int* __restrict__ am,
                     const float* __restrict__ w_a,
                     const float* __restrict__ query,
                     float* __restrict__ Ews,
                     float* __restrict__ Cws) {
    const int blk  = blockIdx.x;           // 0..255
    const int b    = blk >> 7;             // 128 chunks per batch
    const int c    = blk & 127;
    const int j0   = c * CH;
    const int tid  = threadIdx.x;          // 0..255
    const int a    = tid & 127;
    const int half = tid >> 7;

    __shared__ float xs[CH][HH];           // 4 KB
    __shared__ float sred[CH][2][AA];      // 4 KB
    __shared__ float Wl[CH];

    // stage 4 x-rows (contiguous 4 KB) as float4, coalesced
    const float4* xr4 = (const float4*)(x + (size_t)(b * SS + j0) * HH);
    ((float4*)&xs[0][0])[tid] = xr4[tid];
    __syncthreads();

    float acc0 = 0.f, acc1 = 0.f, acc2 = 0.f, acc3 = 0.f;
    const int hbase = half * 128;
    for (int hh = 0; hh < 128; hh += 4) {
        const int h = hbase + hh;
        const float w0 = w_a[(h + 0) * AA + a];   // coalesced, L2-hot
        const float w1 = w_a[(h + 1) * AA + a];
        const float w2 = w_a[(h + 2) * AA + a];
        const float w3 = w_a[(h + 3) * AA + a];
        const float4 x0 = *(const float4*)&xs[0][h];   // LDS broadcast
        const float4 x1 = *(const float4*)&xs[1][h];
        const float4 x2 = *(const float4*)&xs[2][h];
        const float4 x3 = *(const float4*)&xs[3][h];
        acc0 = fmaf(x0.x, w0, fmaf(x0.y, w1, fmaf(x0.z, w2, fmaf(x0.w, w3, acc0))));
        acc1 = fmaf(x1.x, w0, fmaf(x1.y, w1, fmaf(x1.z, w2, fmaf(x1.w, w3, acc1))));
        acc2 = fmaf(x2.x, w0, fmaf(x2.y, w1, fmaf(x2.z, w2, fmaf(x2.w, w3, acc2))));
        acc3 = fmaf(x3.x, w0, fmaf(x3.y, w1, fmaf(x3.z, w2, fmaf(x3.w, w3, acc3))));
    }
    sred[0][half][a] = acc0;
    sred[1][half][a] = acc1;
    sred[2][half][a] = acc2;
    sred[3][half][a] = acc3;
    __syncthreads();

    // wave wvi reduces row r=wvi; lane covers a in {lane, lane+64}
    const int wvi  = tid >> 6;
    const int lane = tid & 63;
    {
        const int r = wvi;
        const float f0 = sred[r][0][lane]      + sred[r][1][lane];
        const float f1 = sred[r][0][lane + 64] + sred[r][1][lane + 64];
        float v = tanhf(f0) * query[lane] + tanhf(f1) * query[lane + 64];
        for (int off = 32; off > 0; off >>= 1)
            v += __shfl_down(v, off, 64);
        if (lane == 0) {
            const float e = expf(v);
            Wl[r] = am[b * SS + j0 + r] ? e : 0.f;
            Ews[b * SS + j0 + r] = e;
        }
    }
    __syncthreads();

    // chunk partial C[h] = sum_r W[r] * x[r][h]; thread tid = h
    const float cacc = fmaf(Wl[0], xs[0][tid],
                       fmaf(Wl[1], xs[1][tid],
                       fmaf(Wl[2], xs[2][tid],
                            Wl[3] * xs[3][tid])));
    Cws[(size_t)(b * NCH + c) * HH + tid] = cacc;
}

// ---------------------------------------------------------------------------
// Kernel 2 (256 blocks x 256 thr; 4 output rows i0..i0+3, chunk-aligned):
//   P_i = sum_{j<=i} E[j]
//   d[i,j] = (j<=i && am_i && am_j) ? E[j]/P_i : 0      (float4 stores)
//   a[i,h] = am_i/P_i * ( sum_{cc < i0/4} C[cc][h] + incremental rows )
// [R5 measured-best body — 4-way ILP chunk loop.]
// ---------------------------------------------------------------------------
__global__ void k_out(const float* __restrict__ Ews,
                      const float* __restrict__ Cws,
                      const int* __restrict__ am,
                      const float* __restrict__ x,
                      float* __restrict__ dout,
                      float* __restrict__ aout) {
    const int blk  = blockIdx.x;           // 0..255
    const int b    = blk >> 7;
    const int i0   = (blk & 127) << 2;
    const int tid  = threadIdx.x;          // 0..255
    const int lane = tid & 63;
    const int wvi  = tid >> 6;

    __shared__ float Es[SS];
    __shared__ float Ws[SS];
    __shared__ float red[4];
    __shared__ float Pinv[4];

    const float e0 = Ews[b * SS + tid];
    const float e1 = Ews[b * SS + tid + 256];
    const int  am0 = am[b * SS + tid];
    const int  am1 = am[b * SS + tid + 256];
    Es[tid] = e0;             Es[tid + 256] = e1;
    Ws[tid] = am0 ? e0 : 0.f; Ws[tid + 256] = am1 ? e1 : 0.f;

    // P_base = sum_{j<=i0} E[j]
    float p = ((tid <= i0) ? e0 : 0.f) + ((tid + 256 <= i0) ? e1 : 0.f);
    for (int off = 32; off > 0; off >>= 1)
        p += __shfl_down(p, off, 64);
    if (lane == 0) red[wvi] = p;
    __syncthreads();
    if (tid == 0) {
        const float P0 = red[0] + red[1] + red[2] + red[3];
        const float P1 = P0 + Es[i0 + 1];
        const float P2 = P1 + Es[i0 + 2];
        const float P3 = P2 + Es[i0 + 3];
        Pinv[0] = 1.f / P0; Pinv[1] = 1.f / P1;
        Pinv[2] = 1.f / P2; Pinv[3] = 1.f / P3;
    }
    __syncthreads();

    const int* amg = am + b * SS;
    int ami[4];
#pragma unroll
    for (int r = 0; r < 4; ++r) ami[r] = amg[i0 + r];

    // ---- d rows: float4 stores. 128 float4/row; thread -> (row-half, col4).
    const size_t drow = (size_t)(b * SS + i0) * SS;
    const int c4  = tid & 127;
    const int jc  = c4 << 2;
    const float4 wv4 = *(const float4*)&Ws[jc];
#pragma unroll
    for (int pp = 0; pp < 2; ++pp) {
        const int   r  = (tid >> 7) + 2 * pp;
        const int   i  = i0 + r;
        const float pv = Pinv[r];
        const bool  on = ami[r] != 0;
        float4 o;
        o.x = (on && jc + 0 <= i) ? wv4.x * pv : 0.f;
        o.y = (on && jc + 1 <= i) ? wv4.y * pv : 0.f;
        o.z = (on && jc + 2 <= i) ? wv4.z * pv : 0.f;
        o.w = (on && jc + 3 <= i) ? wv4.w * pv : 0.f;
        *(float4*)&dout[drow + (size_t)r * SS + jc] = o;
    }

    // ---- a rows: chunk-aligned prefix via C (4-way ILP), then 4 raw rows
    const int nfull = i0 >> 2;             // chunks strictly below i0
    const float* xb = x + (size_t)b * SS * HH + tid;
    const float* Cb = Cws + (size_t)b * NCH * HH + tid;

    float s0 = 0.f, s1 = 0.f, s2 = 0.f, s3 = 0.f;
    int cc = 0;
    for (; cc + 4 <= nfull; cc += 4) {
        s0 += Cb[(size_t)(cc + 0) * HH];
        s1 += Cb[(size_t)(cc + 1) * HH];
        s2 += Cb[(size_t)(cc + 2) * HH];
        s3 += Cb[(size_t)(cc + 3) * HH];
    }
    for (; cc < nfull; ++cc)
        s0 += Cb[(size_t)cc * HH];
    const float base = (s0 + s1) + (s2 + s3);

    const float a0v = fmaf(Ws[i0],     xb[(size_t)(i0)     * HH], base);
    const float a1v = fmaf(Ws[i0 + 1], xb[(size_t)(i0 + 1) * HH], a0v);
    const float a2v = fmaf(Ws[i0 + 2], xb[(size_t)(i0 + 2) * HH], a1v);
    const float a3v = fmaf(Ws[i0 + 3], xb[(size_t)(i0 + 3) * HH], a2v);

    const size_t arow = (size_t)(b * SS + i0) * HH + tid;
    const float av[4] = {a0v, a1v, a2v, a3v};
#pragma unroll
    for (int r = 0; r < 4; ++r)
        aout[arow + (size_t)r * HH] = ami[r] ? av[r] * Pinv[r] : 0.f;
}

// ---------------------------------------------------------------------------
extern "C" void kernel_launch(void* const* d_in, const int* in_sizes, int n_in,
                              void* d_out, int out_size, void* d_ws, size_t ws_size,
                              hipStream_t stream) {
    const float* x     = (const float*)d_in[0];
    const int*   am    = (const int*)d_in[1];
    const float* w_a   = (const float*)d_in[2];
    const float* query = (const float*)d_in[3];

    float* a_out  = (float*)d_out;                   // B*S*H
    float* d_outp = a_out + (size_t)BB * SS * HH;    // B*S*S

    float* Ews = (float*)d_ws;                       // B*S floats
    float* Cws = Ews + BB * SS;                      // B*NCH*H floats (256 KB)

    k_tc <<<BB * NCH,    256, 0, stream>>>(x, am, w_a, query, Ews, Cws);
    k_out<<<BB * SS / 4, 256, 0, stream>>>(Ews, Cws, am, x, d_outp, a_out);
}